// Round 10
// baseline (3966.617 us; speedup 1.0000x reference)
//
#include <hip/hip_runtime.h>
#include <cstdint>
#include <cstddef>

#define F_INC 256
#define HDIM 128
#define NLAYER 3
#define EPSV 1e-5f

// ---------------- edge-index dtype detection + conversion ----------------
// Harness contract: integer inputs arrive as int32 (round-5 evidence: detect
// flagged int32; also jax x64-disabled demotes the reference's int64 to int32).
// Detection kept for robustness: interpret first E elements as int64; any value
// outside [0,N) means the data is really int32 pairs.
__global__ void detect_i64_kernel(const long long* __restrict__ p, int E, int N,
                                  int* __restrict__ flag) {
  int i = blockIdx.x * blockDim.x + threadIdx.x;
  if (i < E) {
    long long v = p[i];
    if (v < 0 || v >= (long long)N) atomicOr(flag, 1);
  }
}

__global__ void convert_idx_kernel(const void* __restrict__ p, int E,
                                   const int* __restrict__ flag,
                                   int* __restrict__ src32, int* __restrict__ dst32) {
  int i = blockIdx.x * blockDim.x + threadIdx.x;
  if (i >= E) return;
  if (*flag == 0) {  // data is int64
    const long long* q = (const long long*)p;
    src32[i] = (int)q[i];
    dst32[i] = (int)q[E + i];
  } else {           // data is int32
    const int* q = (const int*)p;
    src32[i] = q[i];
    dst32[i] = q[E + i];
  }
}

// ---------------- BN statistics (training mode, over node dim) ----------------
template<int F>
__global__ void bn_stats_kernel(const float* __restrict__ h, int nrows, int rowsPerBlock,
                                float* __restrict__ sums /* [2F]: sum, sumsq */) {
  int f  = threadIdx.x % F;
  int rl = threadIdx.x / F;
  const int R = 256 / F;
  int r0 = blockIdx.x * rowsPerBlock;
  int r1 = min(r0 + rowsPerBlock, nrows);
  float s = 0.f, q = 0.f;
  for (int r = r0 + rl; r < r1; r += R) {
    float v = h[(size_t)r * F + f];
    s += v; q += v * v;
  }
  atomicAdd(&sums[f], s);
  atomicAdd(&sums[F + f], q);
}

template<int F>
__global__ void bn_finalize_kernel(const float* __restrict__ sums, const float* __restrict__ g,
                                   const float* __restrict__ b, int nrows,
                                   float* __restrict__ svec, float* __restrict__ shvec) {
  int f = threadIdx.x;
  float mean = sums[f] / (float)nrows;
  float var  = sums[F + f] / (float)nrows - mean * mean;
  var = fmaxf(var, 0.f);
  float sc = g[f] * rsqrtf(var + EPSV);
  svec[f]  = sc;
  shvec[f] = b[f] - mean * sc;
}

// cvec[j] = (base ? base[j] : 0) + sum_k shvec[k] * W[k,j]
__global__ void fold_bias_kernel(const float* __restrict__ shvec, const float* __restrict__ W,
                                 int K, const float* __restrict__ base, float* __restrict__ cvec) {
  int j = threadIdx.x;
  float acc = base ? base[j] : 0.f;
  for (int k = 0; k < K; ++k) acc += shvec[k] * W[(size_t)k * HDIM + j];
  cvec[j] = acc;
}

// ---------------- GEMM: out[n,j] = relu?( sum_k (A[n,k]*s[k]) * W[k,j] + bias[j] )
// BN fold: BN(h)@W = (h*s)@W + sh@W. Staging applies ONLY h*s; the sh@W term
// comes in exactly once via bias = fold_bias(sh, W, base).
// (Round-5 bug: staging applied s*h+sh AND bias had sh@W -> double-counted.)
// BM=64, BN=128, BK=16, 256 threads, 8x4 outputs/thread, fp32 vector ALU.
template<int K, bool RELU>
__launch_bounds__(256)
__global__ void gemm_affine_kernel(const float* __restrict__ A, const float* __restrict__ W,
                                   const float* __restrict__ svec,
                                   const float* __restrict__ bias, float* __restrict__ out, int nrows) {
  __shared__ float As[16][64];    // transposed A tile: As[kk][row]
  __shared__ float Bs[16][128];
  const int t  = threadIdx.x;
  const int tc = t & 31;          // col group: cols 4*tc .. 4*tc+3
  const int tr = t >> 5;          // row group: rows 8*tr .. 8*tr+7
  const int rowBase = blockIdx.x * 64;

  float acc[8][4];
#pragma unroll
  for (int i = 0; i < 8; ++i)
#pragma unroll
    for (int j = 0; j < 4; ++j) acc[i][j] = 0.f;

  const int lrow = t >> 2;        // 0..63 (staging row)
  const int lk   = (t & 3) * 4;   // 0,4,8,12 (staging k offset)

  for (int k0 = 0; k0 < K; k0 += 16) {
    // stage A (scale only — see fold note above)
    {
      int gr = rowBase + lrow;
      float4 v;
      if (gr < nrows) {
        v = *(const float4*)&A[(size_t)gr * K + (k0 + lk)];
        float4 sv = *(const float4*)&svec[k0 + lk];
        v.x *= sv.x;
        v.y *= sv.y;
        v.z *= sv.z;
        v.w *= sv.w;
      } else {
        v = make_float4(0.f, 0.f, 0.f, 0.f);
      }
      As[lk + 0][lrow] = v.x;
      As[lk + 1][lrow] = v.y;
      As[lk + 2][lrow] = v.z;
      As[lk + 3][lrow] = v.w;
    }
    // stage B
#pragma unroll
    for (int i = 0; i < 2; ++i) {
      int idx  = t + i * 256;       // float4 index into 16x128 tile
      int krow = idx >> 5;          // 0..15
      int c    = (idx & 31) * 4;
      *(float4*)&Bs[krow][c] = *(const float4*)&W[(size_t)(k0 + krow) * HDIM + c];
    }
    __syncthreads();
#pragma unroll
    for (int kk = 0; kk < 16; ++kk) {
      float4 a0 = *(const float4*)&As[kk][tr * 8];
      float4 a1 = *(const float4*)&As[kk][tr * 8 + 4];
      float4 b  = *(const float4*)&Bs[kk][tc * 4];
      float ar[8] = {a0.x, a0.y, a0.z, a0.w, a1.x, a1.y, a1.z, a1.w};
      float bc[4] = {b.x, b.y, b.z, b.w};
#pragma unroll
      for (int i = 0; i < 8; ++i)
#pragma unroll
        for (int j = 0; j < 4; ++j) acc[i][j] += ar[i] * bc[j];
    }
    __syncthreads();
  }

  float4 bv = *(const float4*)&bias[tc * 4];
#pragma unroll
  for (int i = 0; i < 8; ++i) {
    int gr = rowBase + tr * 8 + i;
    if (gr < nrows) {
      float4 o;
      o.x = acc[i][0] + bv.x;
      o.y = acc[i][1] + bv.y;
      o.z = acc[i][2] + bv.z;
      o.w = acc[i][3] + bv.w;
      if (RELU) {
        o.x = fmaxf(o.x, 0.f); o.y = fmaxf(o.y, 0.f);
        o.z = fmaxf(o.z, 0.f); o.w = fmaxf(o.w, 0.f);
      }
      *(float4*)&out[(size_t)gr * HDIM + tc * 4] = o;
    }
  }
}

// ---------------- degree / norm ----------------
__global__ void init_deg_kernel(float* __restrict__ deg, int n) {
  int i = blockIdx.x * blockDim.x + threadIdx.x;
  if (i < n) deg[i] = 1.0f;   // self loop
}
__global__ void deg_atomic_kernel(const int* __restrict__ dst, float* __restrict__ deg, int E) {
  int e = blockIdx.x * blockDim.x + threadIdx.x;
  if (e < E) atomicAdd(&deg[dst[e]], 1.0f);
}
__global__ void dinv_kernel(float* __restrict__ deg, int n) {
  int i = blockIdx.x * blockDim.x + threadIdx.x;
  if (i < n) deg[i] = rsqrtf(fmaxf(deg[i], 1.0f));
}

// ---------------- propagation ----------------
// out[n,:] = dinv[n]^2 * t[n,:]   (self-loop term; also serves as the zero-init)
__global__ void self_loop_kernel(const float* __restrict__ t, const float* __restrict__ dinv,
                                 float* __restrict__ out, int n) {
  int i4 = blockIdx.x * blockDim.x + threadIdx.x;       // float4 index
  if (i4 < n * 32) {
    int node = i4 >> 5;
    float w = dinv[node]; w *= w;
    float4 v = ((const float4*)t)[i4];
    v.x *= w; v.y *= w; v.z *= w; v.w *= w;
    ((float4*)out)[i4] = v;
  }
}

// out[dst,:] += dinv[src]*dinv[dst] * t[src,:]   (32 lanes/edge, 4 feats/lane)
__global__ void edge_scatter_kernel(const int* __restrict__ src, const int* __restrict__ dst,
                                    const float* __restrict__ dinv, const float* __restrict__ t,
                                    float* __restrict__ out, int E) {
  int g = blockIdx.x * blockDim.x + threadIdx.x;
  int e = g >> 5;
  int l = g & 31;
  if (e >= E) return;
  int s = src[e], d = dst[e];
  float w = dinv[s] * dinv[d];
  float4 tv = *(const float4*)&t[(size_t)s * HDIM + l * 4];
  float* op = &out[(size_t)d * HDIM + l * 4];
  atomicAdd(op + 0, w * tv.x);
  atomicAdd(op + 1, w * tv.y);
  atomicAdd(op + 2, w * tv.z);
  atomicAdd(op + 3, w * tv.w);
}

__global__ void bias_act_kernel(float* __restrict__ out, const float* __restrict__ b,
                                int n, int relu) {
  int i4 = blockIdx.x * blockDim.x + threadIdx.x;
  if (i4 < n * 32) {
    int j4 = i4 & 31;
    float4 bv = ((const float4*)b)[j4];
    float4 v = ((float4*)out)[i4];
    v.x += bv.x; v.y += bv.y; v.z += bv.z; v.w += bv.w;
    if (relu) {
      v.x = fmaxf(v.x, 0.f); v.y = fmaxf(v.y, 0.f);
      v.z = fmaxf(v.z, 0.f); v.w = fmaxf(v.w, 0.f);
    }
    ((float4*)out)[i4] = v;
  }
}

// ---------------- link scoring: sigmoid(dot(h[src], h[dst])) ----------------
__global__ void edge_score_kernel(const int* __restrict__ src, const int* __restrict__ dst,
                                  const float* __restrict__ h, float* __restrict__ out, int E) {
  int g = blockIdx.x * blockDim.x + threadIdx.x;
  int e = g >> 6;
  int l = g & 63;
  if (e >= E) return;
  int s = src[e], d = dst[e];
  const float* hs = &h[(size_t)s * HDIM];
  const float* hd = &h[(size_t)d * HDIM];
  float sum = hs[l] * hd[l] + hs[l + 64] * hd[l + 64];
#pragma unroll
  for (int off = 32; off >= 1; off >>= 1) sum += __shfl_xor(sum, off);
  if (l == 0) out[e] = 1.0f / (1.0f + expf(-sum));
}

// ---------------- launch ----------------
extern "C" void kernel_launch(void* const* d_in, const int* in_sizes, int n_in,
                              void* d_out, int out_size, void* d_ws, size_t ws_size,
                              hipStream_t stream) {
  const float* x     = (const float*)d_in[0];
  const void*  ei    = d_in[1];
  const float* bn_g  = (const float*)d_in[2];
  const float* bn_b  = (const float*)d_in[3];
  const float* Wf    = (const float*)d_in[4];
  const float* bf    = (const float*)d_in[5];
  const float* bns_g = (const float*)d_in[6];
  const float* bns_b = (const float*)d_in[7];
  const float* Ws    = (const float*)d_in[8];
  const float* bs    = (const float*)d_in[9];
  float* score_out   = (float*)d_out;

  const int N = in_sizes[0] / F_INC;
  const int E = in_sizes[1] / 2;

  const size_t nh = (size_t)N * HDIM;
  float* ws    = (float*)d_ws;
  float* bufA  = ws;
  float* bufB  = bufA + nh;
  float* bufC  = bufB + nh;
  float* dinv  = bufC + nh;
  float* sums  = dinv + N;            // 2*F_INC floats
  float* svec  = sums + 2 * F_INC;    // F_INC
  float* shvec = svec + F_INC;        // F_INC
  float* cvec  = shvec + F_INC;       // HDIM
  int*   src   = (int*)(cvec + HDIM);
  int*   dst   = src + E;
  int*   flag  = dst + E;

  const int nB  = (N + 255) / 256;
  const int eB  = (E + 255) / 256;
  const int gB  = (N + 63) / 64;
  const int b4  = (int)(((size_t)N * 32 + 255) / 256);
  const int rpb = (N + 255) / 256;

  // edge-index dtype detection + conversion to int32 src/dst
  hipMemsetAsync(flag, 0, sizeof(int), stream);
  detect_i64_kernel<<<eB, 256, 0, stream>>>((const long long*)ei, E, N, flag);
  convert_idx_kernel<<<eB, 256, 0, stream>>>(ei, E, flag, src, dst);

  // degree / dinv
  init_deg_kernel<<<nB, 256, 0, stream>>>(dinv, N);
  deg_atomic_kernel<<<eB, 256, 0, stream>>>(dst, dinv, E);
  dinv_kernel<<<nB, 256, 0, stream>>>(dinv, N);

  // feature BN (folded) + feature GEMM + relu
  hipMemsetAsync(sums, 0, 2 * F_INC * sizeof(float), stream);
  bn_stats_kernel<F_INC><<<256, 256, 0, stream>>>(x, N, rpb, sums);
  bn_finalize_kernel<F_INC><<<1, F_INC, 0, stream>>>(sums, bn_g, bn_b, N, svec, shvec);
  fold_bias_kernel<<<1, HDIM, 0, stream>>>(shvec, Wf, F_INC, bf, cvec);
  gemm_affine_kernel<F_INC, true><<<gB, 256, 0, stream>>>(x, Wf, svec, cvec, bufA, N);

  float* h    = bufA;
  float* tbuf = bufB;
  float* obuf = bufC;

  for (int i = 0; i < NLAYER; ++i) {
    const float* Wi = Ws + (size_t)i * HDIM * HDIM;
    hipMemsetAsync(sums, 0, 2 * HDIM * sizeof(float), stream);
    bn_stats_kernel<HDIM><<<256, 256, 0, stream>>>(h, N, rpb, sums);
    bn_finalize_kernel<HDIM><<<1, HDIM, 0, stream>>>(sums, bns_g + i * HDIM, bns_b + i * HDIM,
                                                     N, svec, shvec);
    fold_bias_kernel<<<1, HDIM, 0, stream>>>(shvec, Wi, HDIM, nullptr, cvec);
    gemm_affine_kernel<HDIM, false><<<gB, 256, 0, stream>>>(h, Wi, svec, cvec, tbuf, N);
    self_loop_kernel<<<b4, 256, 0, stream>>>(tbuf, dinv, obuf, N);
    {
      long long tt = (long long)E * 32;
      int eb2 = (int)((tt + 255) / 256);
      edge_scatter_kernel<<<eb2, 256, 0, stream>>>(src, dst, dinv, tbuf, obuf, E);
    }
    bias_act_kernel<<<b4, 256, 0, stream>>>(obuf, bs + i * HDIM, N, (i < NLAYER - 1) ? 1 : 0);
    // rotate: new h is obuf; old h buffer becomes the next scatter target
    float* tmp = h;
    h = obuf;
    obuf = tmp;
  }

  {
    long long tt = (long long)E * 64;
    int eb2 = (int)((tt + 255) / 256);
    edge_score_kernel<<<eb2, 256, 0, stream>>>(src, dst, h, score_out, E);
  }
}

// Round 11
// 1134.245 us; speedup vs baseline: 3.4971x; 3.4971x over previous
//
#include <hip/hip_runtime.h>
#include <cstdint>
#include <cstddef>

#define F_INC 256
#define HDIM 128
#define NLAYER 3
#define EPSV 1e-5f

// ---------------- edge-index dtype detection + conversion ----------------
__global__ void detect_i64_kernel(const long long* __restrict__ p, int E, int N,
                                  int* __restrict__ flag) {
  int i = blockIdx.x * blockDim.x + threadIdx.x;
  if (i < E) {
    long long v = p[i];
    if (v < 0 || v >= (long long)N) atomicOr(flag, 1);
  }
}

__global__ void convert_idx_kernel(const void* __restrict__ p, int E,
                                   const int* __restrict__ flag,
                                   int* __restrict__ src32, int* __restrict__ dst32) {
  int i = blockIdx.x * blockDim.x + threadIdx.x;
  if (i >= E) return;
  if (*flag == 0) {  // data is int64
    const long long* q = (const long long*)p;
    src32[i] = (int)q[i];
    dst32[i] = (int)q[E + i];
  } else {           // data is int32
    const int* q = (const int*)p;
    src32[i] = q[i];
    dst32[i] = q[E + i];
  }
}

// ---------------- BN statistics (training mode, over node dim) ----------------
template<int F>
__global__ void bn_stats_kernel(const float* __restrict__ h, int nrows, int rowsPerBlock,
                                float* __restrict__ sums /* [2F]: sum, sumsq */) {
  int f  = threadIdx.x % F;
  int rl = threadIdx.x / F;
  const int R = 256 / F;
  int r0 = blockIdx.x * rowsPerBlock;
  int r1 = min(r0 + rowsPerBlock, nrows);
  float s = 0.f, q = 0.f;
  for (int r = r0 + rl; r < r1; r += R) {
    float v = h[(size_t)r * F + f];
    s += v; q += v * v;
  }
  atomicAdd(&sums[f], s);
  atomicAdd(&sums[F + f], q);
}

template<int F>
__global__ void bn_finalize_kernel(const float* __restrict__ sums, const float* __restrict__ g,
                                   const float* __restrict__ b, int nrows,
                                   float* __restrict__ svec, float* __restrict__ shvec) {
  int f = threadIdx.x;
  float mean = sums[f] / (float)nrows;
  float var  = sums[F + f] / (float)nrows - mean * mean;
  var = fmaxf(var, 0.f);
  float sc = g[f] * rsqrtf(var + EPSV);
  svec[f]  = sc;
  shvec[f] = b[f] - mean * sc;
}

// cvec[j] = (base ? base[j] : 0) + sum_k shvec[k] * W[k,j]
__global__ void fold_bias_kernel(const float* __restrict__ shvec, const float* __restrict__ W,
                                 int K, const float* __restrict__ base, float* __restrict__ cvec) {
  int j = threadIdx.x;
  float acc = base ? base[j] : 0.f;
  for (int k = 0; k < K; ++k) acc += shvec[k] * W[(size_t)k * HDIM + j];
  cvec[j] = acc;
}

// ---------------- GEMM: out[n,j] = relu?( sum_k (A[n,k]*s[k]) * W[k,j] + bias[j] )
// BN fold: BN(h)@W = (h*s)@W + sh@W; sh@W enters exactly once via bias.
template<int K, bool RELU>
__launch_bounds__(256)
__global__ void gemm_affine_kernel(const float* __restrict__ A, const float* __restrict__ W,
                                   const float* __restrict__ svec,
                                   const float* __restrict__ bias, float* __restrict__ out, int nrows) {
  __shared__ float As[16][64];    // transposed A tile: As[kk][row]
  __shared__ float Bs[16][128];
  const int t  = threadIdx.x;
  const int tc = t & 31;
  const int tr = t >> 5;
  const int rowBase = blockIdx.x * 64;

  float acc[8][4];
#pragma unroll
  for (int i = 0; i < 8; ++i)
#pragma unroll
    for (int j = 0; j < 4; ++j) acc[i][j] = 0.f;

  const int lrow = t >> 2;
  const int lk   = (t & 3) * 4;

  for (int k0 = 0; k0 < K; k0 += 16) {
    {
      int gr = rowBase + lrow;
      float4 v;
      if (gr < nrows) {
        v = *(const float4*)&A[(size_t)gr * K + (k0 + lk)];
        float4 sv = *(const float4*)&svec[k0 + lk];
        v.x *= sv.x; v.y *= sv.y; v.z *= sv.z; v.w *= sv.w;
      } else {
        v = make_float4(0.f, 0.f, 0.f, 0.f);
      }
      As[lk + 0][lrow] = v.x;
      As[lk + 1][lrow] = v.y;
      As[lk + 2][lrow] = v.z;
      As[lk + 3][lrow] = v.w;
    }
#pragma unroll
    for (int i = 0; i < 2; ++i) {
      int idx  = t + i * 256;
      int krow = idx >> 5;
      int c    = (idx & 31) * 4;
      *(float4*)&Bs[krow][c] = *(const float4*)&W[(size_t)(k0 + krow) * HDIM + c];
    }
    __syncthreads();
#pragma unroll
    for (int kk = 0; kk < 16; ++kk) {
      float4 a0 = *(const float4*)&As[kk][tr * 8];
      float4 a1 = *(const float4*)&As[kk][tr * 8 + 4];
      float4 b  = *(const float4*)&Bs[kk][tc * 4];
      float ar[8] = {a0.x, a0.y, a0.z, a0.w, a1.x, a1.y, a1.z, a1.w};
      float bc[4] = {b.x, b.y, b.z, b.w};
#pragma unroll
      for (int i = 0; i < 8; ++i)
#pragma unroll
        for (int j = 0; j < 4; ++j) acc[i][j] += ar[i] * bc[j];
    }
    __syncthreads();
  }

  float4 bv = *(const float4*)&bias[tc * 4];
#pragma unroll
  for (int i = 0; i < 8; ++i) {
    int gr = rowBase + tr * 8 + i;
    if (gr < nrows) {
      float4 o;
      o.x = acc[i][0] + bv.x;
      o.y = acc[i][1] + bv.y;
      o.z = acc[i][2] + bv.z;
      o.w = acc[i][3] + bv.w;
      if (RELU) {
        o.x = fmaxf(o.x, 0.f); o.y = fmaxf(o.y, 0.f);
        o.z = fmaxf(o.z, 0.f); o.w = fmaxf(o.w, 0.f);
      }
      *(float4*)&out[(size_t)gr * HDIM + tc * 4] = o;
    }
  }
}

// ---------------- degree / norm ----------------
__global__ void init_deg_kernel(float* __restrict__ deg, int n) {
  int i = blockIdx.x * blockDim.x + threadIdx.x;
  if (i < n) deg[i] = 1.0f;   // self loop
}
__global__ void deg_atomic_kernel(const int* __restrict__ dst, float* __restrict__ deg, int E) {
  int e = blockIdx.x * blockDim.x + threadIdx.x;
  if (e < E) atomicAdd(&deg[dst[e]], 1.0f);
}
__global__ void dinv_kernel(float* __restrict__ deg, int n) {
  int i = blockIdx.x * blockDim.x + threadIdx.x;
  if (i < n) deg[i] = rsqrtf(fmaxf(deg[i], 1.0f));
}

// ---------------- CSR build (once; reused across all 3 layers) ----------------
// Exclusive prefix sum of in-degrees (deg[i] = 1 + indeg at this point).
// Single 1024-thread block; shfl wave scans + LDS cross-wave combine.
__global__ __launch_bounds__(1024)
void scan_offsets_kernel(const float* __restrict__ deg, int n,
                         int* __restrict__ offs, int* __restrict__ cursor) {
  __shared__ int woff_s[16];
  __shared__ int btot;
  __shared__ int carry;
  const int t = threadIdx.x;
  const int lane = t & 63;
  const int wv = t >> 6;
  if (t == 0) carry = 0;
  __syncthreads();
  for (int base = 0; base < n; base += 1024) {
    int i = base + t;
    int v = (i < n) ? ((int)(deg[i] + 0.5f) - 1) : 0;
    int incl = v;
#pragma unroll
    for (int o = 1; o < 64; o <<= 1) {
      int y = __shfl_up(incl, o);
      if (lane >= o) incl += y;
    }
    if (lane == 63) woff_s[wv] = incl;     // wave totals
    __syncthreads();
    if (t < 16) {
      int x = woff_s[t];
      int xin = x;
#pragma unroll
      for (int o = 1; o < 16; o <<= 1) {
        int y = __shfl_up(xin, o);
        if (t >= o) xin += y;
      }
      woff_s[t] = xin - x;                 // exclusive wave offset
      if (t == 15) btot = xin;             // chunk total
    }
    __syncthreads();
    int excl = carry + woff_s[wv] + (incl - v);
    if (i < n) { offs[i] = excl; cursor[i] = excl; }
    __syncthreads();
    if (t == 0) carry += btot;
    __syncthreads();
  }
  if (t == 0) offs[n] = carry;
}

// Place each edge into its dst segment; weight = dinv[s]*dinv[d] (layer-invariant).
__global__ void csr_fill_kernel(const int* __restrict__ src, const int* __restrict__ dst,
                                const float* __restrict__ dinv, int* __restrict__ cursor,
                                int* __restrict__ eperm, float* __restrict__ wperm, int E) {
  int e = blockIdx.x * blockDim.x + threadIdx.x;
  if (e >= E) return;
  int s = src[e], d = dst[e];
  int slot = atomicAdd(&cursor[d], 1);
  eperm[slot] = s;
  wperm[slot] = dinv[s] * dinv[d];
}

// ---------------- fused propagation: self-loop + gather-sum + bias (+relu) ----
// One wave per node; lane l holds feats [2l, 2l+1]. Atomic-free.
// out[n] = dinv[n]^2 * t[n] + sum_e w_e * t[src_e] + bias  (relu optional)
__global__ __launch_bounds__(256)
void gcn_gather_kernel(const float* __restrict__ t, const int* __restrict__ offs,
                       const int* __restrict__ eperm, const float* __restrict__ wperm,
                       const float* __restrict__ dinv, const float* __restrict__ bias,
                       float* __restrict__ out, int n, int relu) {
  int gw = (int)((blockIdx.x * blockDim.x + threadIdx.x) >> 6);
  int lane = threadIdx.x & 63;
  if (gw >= n) return;
  float w0 = dinv[gw]; w0 *= w0;
  float2 tv = *(const float2*)&t[(size_t)gw * HDIM + lane * 2];
  float ax = w0 * tv.x, ay = w0 * tv.y;
  int e = offs[gw], e1 = offs[gw + 1];
  for (; e + 1 < e1; e += 2) {
    int s0 = eperm[e], s1 = eperm[e + 1];
    float wa = wperm[e], wb = wperm[e + 1];
    float2 v0 = *(const float2*)&t[(size_t)s0 * HDIM + lane * 2];
    float2 v1 = *(const float2*)&t[(size_t)s1 * HDIM + lane * 2];
    ax += wa * v0.x + wb * v1.x;
    ay += wa * v0.y + wb * v1.y;
  }
  if (e < e1) {
    int s0 = eperm[e]; float wa = wperm[e];
    float2 v0 = *(const float2*)&t[(size_t)s0 * HDIM + lane * 2];
    ax += wa * v0.x; ay += wa * v0.y;
  }
  float2 bv = *(const float2*)&bias[lane * 2];
  ax += bv.x; ay += bv.y;
  if (relu) { ax = fmaxf(ax, 0.f); ay = fmaxf(ay, 0.f); }
  float2 o; o.x = ax; o.y = ay;
  *(float2*)&out[(size_t)gw * HDIM + lane * 2] = o;
}

// ---------------- link scoring: sigmoid(dot(h[src], h[dst])) ----------------
__global__ void edge_score_kernel(const int* __restrict__ src, const int* __restrict__ dst,
                                  const float* __restrict__ h, float* __restrict__ out, int E) {
  int g = blockIdx.x * blockDim.x + threadIdx.x;
  int e = g >> 6;
  int l = g & 63;
  if (e >= E) return;
  int s = src[e], d = dst[e];
  const float* hs = &h[(size_t)s * HDIM];
  const float* hd = &h[(size_t)d * HDIM];
  float sum = hs[l] * hd[l] + hs[l + 64] * hd[l + 64];
#pragma unroll
  for (int off = 32; off >= 1; off >>= 1) sum += __shfl_xor(sum, off);
  if (l == 0) out[e] = 1.0f / (1.0f + expf(-sum));
}

// ---------------- launch ----------------
extern "C" void kernel_launch(void* const* d_in, const int* in_sizes, int n_in,
                              void* d_out, int out_size, void* d_ws, size_t ws_size,
                              hipStream_t stream) {
  const float* x     = (const float*)d_in[0];
  const void*  ei    = d_in[1];
  const float* bn_g  = (const float*)d_in[2];
  const float* bn_b  = (const float*)d_in[3];
  const float* Wf    = (const float*)d_in[4];
  const float* bf    = (const float*)d_in[5];
  const float* bns_g = (const float*)d_in[6];
  const float* bns_b = (const float*)d_in[7];
  const float* Ws    = (const float*)d_in[8];
  const float* bs    = (const float*)d_in[9];
  float* score_out   = (float*)d_out;

  const int N = in_sizes[0] / F_INC;
  const int E = in_sizes[1] / 2;

  const size_t nh = (size_t)N * HDIM;
  float* ws     = (float*)d_ws;
  float* bufA   = ws;
  float* bufB   = bufA + nh;
  float* bufC   = bufB + nh;
  float* dinv   = bufC + nh;          // holds deg counts, then rsqrt in place
  float* sums   = dinv + N;           // 2*F_INC floats
  float* svec   = sums + 2 * F_INC;   // F_INC
  float* shvec  = svec + F_INC;       // F_INC
  float* cvec   = shvec + F_INC;      // HDIM
  int*   src    = (int*)(cvec + HDIM);
  int*   dst    = src + E;
  int*   flag   = dst + E;
  int*   offs   = flag + 1;           // N+1
  int*   cursor = offs + (N + 1);     // N
  int*   eperm  = cursor + N;         // E
  float* wperm  = (float*)(eperm + E);// E

  const int nB = (N + 255) / 256;
  const int eB = (E + 255) / 256;
  const int gB = (N + 63) / 64;
  const int rpb = (N + 255) / 256;
  const int gatherB = (N + 3) / 4;    // 4 waves (nodes) per 256-thread block

  // edge-index dtype detection + conversion to int32 src/dst
  hipMemsetAsync(flag, 0, sizeof(int), stream);
  detect_i64_kernel<<<eB, 256, 0, stream>>>((const long long*)ei, E, N, flag);
  convert_idx_kernel<<<eB, 256, 0, stream>>>(ei, E, flag, src, dst);

  // degree -> CSR offsets -> dinv -> CSR fill (weights need dinv)
  init_deg_kernel<<<nB, 256, 0, stream>>>(dinv, N);
  deg_atomic_kernel<<<eB, 256, 0, stream>>>(dst, dinv, E);
  scan_offsets_kernel<<<1, 1024, 0, stream>>>(dinv, N, offs, cursor);
  dinv_kernel<<<nB, 256, 0, stream>>>(dinv, N);
  csr_fill_kernel<<<eB, 256, 0, stream>>>(src, dst, dinv, cursor, eperm, wperm, E);

  // feature BN (folded) + feature GEMM + relu
  hipMemsetAsync(sums, 0, 2 * F_INC * sizeof(float), stream);
  bn_stats_kernel<F_INC><<<256, 256, 0, stream>>>(x, N, rpb, sums);
  bn_finalize_kernel<F_INC><<<1, F_INC, 0, stream>>>(sums, bn_g, bn_b, N, svec, shvec);
  fold_bias_kernel<<<1, HDIM, 0, stream>>>(shvec, Wf, F_INC, bf, cvec);
  gemm_affine_kernel<F_INC, true><<<gB, 256, 0, stream>>>(x, Wf, svec, cvec, bufA, N);

  float* h    = bufA;
  float* tbuf = bufB;
  float* obuf = bufC;

  for (int i = 0; i < NLAYER; ++i) {
    const float* Wi = Ws + (size_t)i * HDIM * HDIM;
    hipMemsetAsync(sums, 0, 2 * HDIM * sizeof(float), stream);
    bn_stats_kernel<HDIM><<<256, 256, 0, stream>>>(h, N, rpb, sums);
    bn_finalize_kernel<HDIM><<<1, HDIM, 0, stream>>>(sums, bns_g + i * HDIM, bns_b + i * HDIM,
                                                     N, svec, shvec);
    fold_bias_kernel<<<1, HDIM, 0, stream>>>(shvec, Wi, HDIM, nullptr, cvec);
    gemm_affine_kernel<HDIM, false><<<gB, 256, 0, stream>>>(h, Wi, svec, cvec, tbuf, N);
    // fused: self-loop + CSR gather + bias (+relu except last layer)
    gcn_gather_kernel<<<gatherB, 256, 0, stream>>>(tbuf, offs, eperm, wperm, dinv,
                                                   bs + i * HDIM, obuf, N,
                                                   (i < NLAYER - 1) ? 1 : 0);
    float* tmp = h;
    h = obuf;
    obuf = tmp;
  }

  {
    long long tt = (long long)E * 64;
    int eb2 = (int)((tt + 255) / 256);
    edge_score_kernel<<<eb2, 256, 0, stream>>>(src, dst, h, score_out, E);
  }
}

// Round 12
// 959.463 us; speedup vs baseline: 4.1342x; 1.1822x over previous
//
#include <hip/hip_runtime.h>
#include <cstdint>
#include <cstddef>

#define F_INC 256
#define HDIM 128
#define NLAYER 3
#define EPSV 1e-5f

// ---------------- edge-index dtype detection + conversion ----------------
__global__ void detect_i64_kernel(const long long* __restrict__ p, int E, int N,
                                  int* __restrict__ flag) {
  int i = blockIdx.x * blockDim.x + threadIdx.x;
  if (i < E) {
    long long v = p[i];
    if (v < 0 || v >= (long long)N) atomicOr(flag, 1);
  }
}

__global__ void convert_idx_kernel(const void* __restrict__ p, int E,
                                   const int* __restrict__ flag,
                                   int* __restrict__ src32, int* __restrict__ dst32) {
  int i = blockIdx.x * blockDim.x + threadIdx.x;
  if (i >= E) return;
  if (*flag == 0) {
    const long long* q = (const long long*)p;
    src32[i] = (int)q[i];
    dst32[i] = (int)q[E + i];
  } else {
    const int* q = (const int*)p;
    src32[i] = q[i];
    dst32[i] = q[E + i];
  }
}

// ---------------- BN statistics (training mode, over node dim) ----------------
template<int F>
__global__ void bn_stats_kernel(const float* __restrict__ h, int nrows, int rowsPerBlock,
                                float* __restrict__ sums /* [2F]: sum, sumsq */) {
  int f  = threadIdx.x % F;
  int rl = threadIdx.x / F;
  const int R = 256 / F;
  int r0 = blockIdx.x * rowsPerBlock;
  int r1 = min(r0 + rowsPerBlock, nrows);
  float s = 0.f, q = 0.f;
  for (int r = r0 + rl; r < r1; r += R) {
    float v = h[(size_t)r * F + f];
    s += v; q += v * v;
  }
  atomicAdd(&sums[f], s);
  atomicAdd(&sums[F + f], q);
}

// Fused: BN finalize (svec, shvec) + bias fold cvec = base + shvec@W.
// Launch with K threads (K = 256 or 128); shvec lives in LDS only.
template<int K>
__global__ void bn_fin_fold_kernel(const float* __restrict__ sums, const float* __restrict__ g,
                                   const float* __restrict__ b, int nrows,
                                   const float* __restrict__ W, const float* __restrict__ base,
                                   float* __restrict__ svec, float* __restrict__ cvec) {
  __shared__ float sh[K];
  int t = threadIdx.x;
  float mean = sums[t] / (float)nrows;
  float var  = sums[K + t] / (float)nrows - mean * mean;
  var = fmaxf(var, 0.f);
  float sc = g[t] * rsqrtf(var + EPSV);
  svec[t] = sc;
  sh[t] = b[t] - mean * sc;
  __syncthreads();
  if (t < HDIM) {
    float acc = base ? base[t] : 0.f;
#pragma unroll 8
    for (int k = 0; k < K; ++k) acc += sh[k] * W[(size_t)k * HDIM + t];
    cvec[t] = acc;
  }
}

// ---------------- GEMM: out[n,j] = relu?( sum_k (A[n,k]*s[k]) * W[k,j] + bias[j] )
// BN fold: BN(h)@W = (h*s)@W + sh@W; sh@W enters exactly once via bias (cvec).
// 128x128 tile, BK=8, 256 threads, 8x8 outputs/thread (128 flops / 4 LDS b128 reads).
template<int K, bool RELU>
__launch_bounds__(256)
__global__ void gemm_affine_kernel(const float* __restrict__ A, const float* __restrict__ W,
                                   const float* __restrict__ svec,
                                   const float* __restrict__ bias, float* __restrict__ out,
                                   int nrows) {
  __shared__ float As[8][128];   // transposed A tile: As[kk][row]
  __shared__ float Bs[8][128];
  const int t  = threadIdx.x;
  const int tx = t & 15;          // col block: cols 8*tx .. 8*tx+7
  const int ty = t >> 4;          // row block: rows 8*ty .. 8*ty+7
  const int rowBase = blockIdx.x * 128;

  float acc[8][8];
#pragma unroll
  for (int i = 0; i < 8; ++i)
#pragma unroll
    for (int j = 0; j < 8; ++j) acc[i][j] = 0.f;

  const int arow = t >> 1;        // 0..127
  const int akk  = (t & 1) * 4;   // 0 or 4
  const int bkk  = t >> 5;        // 0..7
  const int bc   = (t & 31) * 4;  // 0..124

  for (int k0 = 0; k0 < K; k0 += 8) {
    {
      int gr = rowBase + arow;
      float4 v = make_float4(0.f, 0.f, 0.f, 0.f);
      if (gr < nrows) {
        v = *(const float4*)&A[(size_t)gr * K + (k0 + akk)];
        float4 sv = *(const float4*)&svec[k0 + akk];
        v.x *= sv.x; v.y *= sv.y; v.z *= sv.z; v.w *= sv.w;
      }
      As[akk + 0][arow] = v.x;
      As[akk + 1][arow] = v.y;
      As[akk + 2][arow] = v.z;
      As[akk + 3][arow] = v.w;
    }
    *(float4*)&Bs[bkk][bc] = *(const float4*)&W[(size_t)(k0 + bkk) * HDIM + bc];
    __syncthreads();
#pragma unroll
    for (int kk = 0; kk < 8; ++kk) {
      float4 a0 = *(const float4*)&As[kk][ty * 8];
      float4 a1 = *(const float4*)&As[kk][ty * 8 + 4];
      float4 b0 = *(const float4*)&Bs[kk][tx * 8];
      float4 b1 = *(const float4*)&Bs[kk][tx * 8 + 4];
      float ar[8] = {a0.x, a0.y, a0.z, a0.w, a1.x, a1.y, a1.z, a1.w};
      float br[8] = {b0.x, b0.y, b0.z, b0.w, b1.x, b1.y, b1.z, b1.w};
#pragma unroll
      for (int i = 0; i < 8; ++i)
#pragma unroll
        for (int j = 0; j < 8; ++j) acc[i][j] += ar[i] * br[j];
    }
    __syncthreads();
  }

  float4 bv0 = *(const float4*)&bias[tx * 8];
  float4 bv1 = *(const float4*)&bias[tx * 8 + 4];
#pragma unroll
  for (int i = 0; i < 8; ++i) {
    int gr = rowBase + ty * 8 + i;
    if (gr < nrows) {
      float4 o0, o1;
      o0.x = acc[i][0] + bv0.x; o0.y = acc[i][1] + bv0.y;
      o0.z = acc[i][2] + bv0.z; o0.w = acc[i][3] + bv0.w;
      o1.x = acc[i][4] + bv1.x; o1.y = acc[i][5] + bv1.y;
      o1.z = acc[i][6] + bv1.z; o1.w = acc[i][7] + bv1.w;
      if (RELU) {
        o0.x = fmaxf(o0.x, 0.f); o0.y = fmaxf(o0.y, 0.f);
        o0.z = fmaxf(o0.z, 0.f); o0.w = fmaxf(o0.w, 0.f);
        o1.x = fmaxf(o1.x, 0.f); o1.y = fmaxf(o1.y, 0.f);
        o1.z = fmaxf(o1.z, 0.f); o1.w = fmaxf(o1.w, 0.f);
      }
      *(float4*)&out[(size_t)gr * HDIM + tx * 8]     = o0;
      *(float4*)&out[(size_t)gr * HDIM + tx * 8 + 4] = o1;
    }
  }
}

// ---------------- degree / norm ----------------
__global__ void init_deg_kernel(float* __restrict__ deg, int n) {
  int i = blockIdx.x * blockDim.x + threadIdx.x;
  if (i < n) deg[i] = 1.0f;   // self loop
}
__global__ void deg_atomic_kernel(const int* __restrict__ dst, float* __restrict__ deg, int E) {
  int e = blockIdx.x * blockDim.x + threadIdx.x;
  if (e < E) atomicAdd(&deg[dst[e]], 1.0f);
}
__global__ void dinv_kernel(float* __restrict__ deg, int n) {
  int i = blockIdx.x * blockDim.x + threadIdx.x;
  if (i < n) deg[i] = rsqrtf(fmaxf(deg[i], 1.0f));
}

// ---------------- CSR build (once; reused across all 3 layers) ----------------
__global__ __launch_bounds__(1024)
void scan_offsets_kernel(const float* __restrict__ deg, int n,
                         int* __restrict__ offs, int* __restrict__ cursor) {
  __shared__ int woff_s[16];
  __shared__ int btot;
  __shared__ int carry;
  const int t = threadIdx.x;
  const int lane = t & 63;
  const int wv = t >> 6;
  if (t == 0) carry = 0;
  __syncthreads();
  for (int base = 0; base < n; base += 1024) {
    int i = base + t;
    int v = (i < n) ? ((int)(deg[i] + 0.5f) - 1) : 0;
    int incl = v;
#pragma unroll
    for (int o = 1; o < 64; o <<= 1) {
      int y = __shfl_up(incl, o);
      if (lane >= o) incl += y;
    }
    if (lane == 63) woff_s[wv] = incl;
    __syncthreads();
    if (t < 16) {
      int x = woff_s[t];
      int xin = x;
#pragma unroll
      for (int o = 1; o < 16; o <<= 1) {
        int y = __shfl_up(xin, o);
        if (t >= o) xin += y;
      }
      woff_s[t] = xin - x;
      if (t == 15) btot = xin;
    }
    __syncthreads();
    int excl = carry + woff_s[wv] + (incl - v);
    if (i < n) { offs[i] = excl; cursor[i] = excl; }
    __syncthreads();
    if (t == 0) carry += btot;
    __syncthreads();
  }
  if (t == 0) offs[n] = carry;
}

__global__ void csr_fill_kernel(const int* __restrict__ src, const int* __restrict__ dst,
                                const float* __restrict__ dinv, int* __restrict__ cursor,
                                int* __restrict__ eperm, float* __restrict__ wperm, int E) {
  int e = blockIdx.x * blockDim.x + threadIdx.x;
  if (e >= E) return;
  int s = src[e], d = dst[e];
  int slot = atomicAdd(&cursor[d], 1);
  eperm[slot] = s;
  wperm[slot] = dinv[s] * dinv[d];
}

// ---------------- fused propagation: self-loop + gather-sum + bias (+relu) ----
// One wave per node; lane l holds feats [2l, 2l+1]. 4-edge unroll for MLP.
__global__ __launch_bounds__(256)
void gcn_gather_kernel(const float* __restrict__ t, const int* __restrict__ offs,
                       const int* __restrict__ eperm, const float* __restrict__ wperm,
                       const float* __restrict__ dinv, const float* __restrict__ bias,
                       float* __restrict__ out, int n, int relu) {
  int gw = (int)((blockIdx.x * blockDim.x + threadIdx.x) >> 6);
  int lane = threadIdx.x & 63;
  if (gw >= n) return;
  float w0 = dinv[gw]; w0 *= w0;
  float2 tv = *(const float2*)&t[(size_t)gw * HDIM + lane * 2];
  float ax = w0 * tv.x, ay = w0 * tv.y;
  int e = offs[gw], e1 = offs[gw + 1];
  for (; e + 3 < e1; e += 4) {
    int s0 = eperm[e], s1 = eperm[e + 1], s2 = eperm[e + 2], s3 = eperm[e + 3];
    float wa = wperm[e], wb = wperm[e + 1], wc = wperm[e + 2], wd = wperm[e + 3];
    float2 v0 = *(const float2*)&t[(size_t)s0 * HDIM + lane * 2];
    float2 v1 = *(const float2*)&t[(size_t)s1 * HDIM + lane * 2];
    float2 v2 = *(const float2*)&t[(size_t)s2 * HDIM + lane * 2];
    float2 v3 = *(const float2*)&t[(size_t)s3 * HDIM + lane * 2];
    ax += wa * v0.x + wb * v1.x + wc * v2.x + wd * v3.x;
    ay += wa * v0.y + wb * v1.y + wc * v2.y + wd * v3.y;
  }
  for (; e < e1; ++e) {
    int s0 = eperm[e]; float wa = wperm[e];
    float2 v0 = *(const float2*)&t[(size_t)s0 * HDIM + lane * 2];
    ax += wa * v0.x; ay += wa * v0.y;
  }
  float2 bv = *(const float2*)&bias[lane * 2];
  ax += bv.x; ay += bv.y;
  if (relu) { ax = fmaxf(ax, 0.f); ay = fmaxf(ay, 0.f); }
  float2 o; o.x = ax; o.y = ay;
  *(float2*)&out[(size_t)gw * HDIM + lane * 2] = o;
}

// ---------------- link scoring: sigmoid(dot(h[src], h[dst])) ----------------
__global__ void edge_score_kernel(const int* __restrict__ src, const int* __restrict__ dst,
                                  const float* __restrict__ h, float* __restrict__ out, int E) {
  int g = blockIdx.x * blockDim.x + threadIdx.x;
  int e = g >> 6;
  int l = g & 63;
  if (e >= E) return;
  int s = src[e], d = dst[e];
  const float* hs = &h[(size_t)s * HDIM];
  const float* hd = &h[(size_t)d * HDIM];
  float sum = hs[l] * hd[l] + hs[l + 64] * hd[l + 64];
#pragma unroll
  for (int off = 32; off >= 1; off >>= 1) sum += __shfl_xor(sum, off);
  if (l == 0) out[e] = 1.0f / (1.0f + expf(-sum));
}

// ---------------- launch ----------------
extern "C" void kernel_launch(void* const* d_in, const int* in_sizes, int n_in,
                              void* d_out, int out_size, void* d_ws, size_t ws_size,
                              hipStream_t stream) {
  const float* x     = (const float*)d_in[0];
  const void*  ei    = d_in[1];
  const float* bn_g  = (const float*)d_in[2];
  const float* bn_b  = (const float*)d_in[3];
  const float* Wf    = (const float*)d_in[4];
  const float* bf    = (const float*)d_in[5];
  const float* bns_g = (const float*)d_in[6];
  const float* bns_b = (const float*)d_in[7];
  const float* Ws    = (const float*)d_in[8];
  const float* bs    = (const float*)d_in[9];
  float* score_out   = (float*)d_out;

  const int N = in_sizes[0] / F_INC;
  const int E = in_sizes[1] / 2;

  const size_t nh = (size_t)N * HDIM;
  float* ws     = (float*)d_ws;
  float* bufA   = ws;
  float* bufB   = bufA + nh;
  float* bufC   = bufB + nh;
  float* dinv   = bufC + nh;
  float* sums   = dinv + N;           // 2*F_INC floats
  float* svec   = sums + 2 * F_INC;   // F_INC
  float* shvec  = svec + F_INC;       // F_INC (unused now; layout kept)
  float* cvec   = shvec + F_INC;      // HDIM
  int*   src    = (int*)(cvec + HDIM);
  int*   dst    = src + E;
  int*   flag   = dst + E;
  int*   offs   = flag + 1;           // N+1
  int*   cursor = offs + (N + 1);     // N
  int*   eperm  = cursor + N;         // E
  float* wperm  = (float*)(eperm + E);// E

  const int nB = (N + 255) / 256;
  const int eB = (E + 255) / 256;
  const int gB = (N + 127) / 128;     // 128-row GEMM tiles
  const int rpb = (N + 255) / 256;
  const int gatherB = (N + 3) / 4;

  // edge-index dtype detection + conversion to int32 src/dst
  hipMemsetAsync(flag, 0, sizeof(int), stream);
  detect_i64_kernel<<<eB, 256, 0, stream>>>((const long long*)ei, E, N, flag);
  convert_idx_kernel<<<eB, 256, 0, stream>>>(ei, E, flag, src, dst);

  // degree -> CSR offsets -> dinv -> CSR fill
  init_deg_kernel<<<nB, 256, 0, stream>>>(dinv, N);
  deg_atomic_kernel<<<eB, 256, 0, stream>>>(dst, dinv, E);
  scan_offsets_kernel<<<1, 1024, 0, stream>>>(dinv, N, offs, cursor);
  dinv_kernel<<<nB, 256, 0, stream>>>(dinv, N);
  csr_fill_kernel<<<eB, 256, 0, stream>>>(src, dst, dinv, cursor, eperm, wperm, E);

  // feature BN (folded) + feature GEMM + relu
  hipMemsetAsync(sums, 0, 2 * F_INC * sizeof(float), stream);
  bn_stats_kernel<F_INC><<<256, 256, 0, stream>>>(x, N, rpb, sums);
  bn_fin_fold_kernel<F_INC><<<1, F_INC, 0, stream>>>(sums, bn_g, bn_b, N, Wf, bf, svec, cvec);
  gemm_affine_kernel<F_INC, true><<<gB, 256, 0, stream>>>(x, Wf, svec, cvec, bufA, N);

  float* h    = bufA;
  float* tbuf = bufB;
  float* obuf = bufC;

  for (int i = 0; i < NLAYER; ++i) {
    const float* Wi = Ws + (size_t)i * HDIM * HDIM;
    hipMemsetAsync(sums, 0, 2 * HDIM * sizeof(float), stream);
    bn_stats_kernel<HDIM><<<256, 256, 0, stream>>>(h, N, rpb, sums);
    bn_fin_fold_kernel<HDIM><<<1, HDIM, 0, stream>>>(sums, bns_g + i * HDIM, bns_b + i * HDIM,
                                                     N, Wi, nullptr, svec, cvec);
    gemm_affine_kernel<HDIM, false><<<gB, 256, 0, stream>>>(h, Wi, svec, cvec, tbuf, N);
    gcn_gather_kernel<<<gatherB, 256, 0, stream>>>(tbuf, offs, eperm, wperm, dinv,
                                                   bs + i * HDIM, obuf, N,
                                                   (i < NLAYER - 1) ? 1 : 0);
    float* tmp = h;
    h = obuf;
    obuf = tmp;
  }

  {
    long long tt = (long long)E * 64;
    int eb2 = (int)((tt + 255) / 256);
    edge_score_kernel<<<eb2, 256, 0, stream>>>(src, dst, h, score_out, E);
  }
}

// Round 13
// 922.798 us; speedup vs baseline: 4.2985x; 1.0397x over previous
//
#include <hip/hip_runtime.h>
#include <cstdint>
#include <cstddef>

#define F_INC 256
#define HDIM 128
#define NLAYER 3
#define EPSV 1e-5f

typedef unsigned short ushort_t;
typedef unsigned int uint_t;

__device__ __forceinline__ ushort_t f2bf(float x) {   // round-to-nearest-even
  uint_t u = __float_as_uint(x);
  return (ushort_t)((u + 0x7FFFu + ((u >> 16) & 1u)) >> 16);
}
__device__ __forceinline__ float bf2f(uint_t h) {
  return __uint_as_float(h << 16);
}

// ---------------- edge-index dtype detection + conversion ----------------
__global__ void detect_i64_kernel(const long long* __restrict__ p, int E, int N,
                                  int* __restrict__ flag) {
  int i = blockIdx.x * blockDim.x + threadIdx.x;
  if (i < E) {
    long long v = p[i];
    if (v < 0 || v >= (long long)N) atomicOr(flag, 1);
  }
}

__global__ void convert_idx_kernel(const void* __restrict__ p, int E,
                                   const int* __restrict__ flag,
                                   int* __restrict__ src32, int* __restrict__ dst32) {
  int i = blockIdx.x * blockDim.x + threadIdx.x;
  if (i >= E) return;
  if (*flag == 0) {
    const long long* q = (const long long*)p;
    src32[i] = (int)q[i];
    dst32[i] = (int)q[E + i];
  } else {
    const int* q = (const int*)p;
    src32[i] = q[i];
    dst32[i] = q[E + i];
  }
}

// ---------------- BN statistics ----------------
template<int F>
__global__ void bn_stats_kernel(const float* __restrict__ h, int nrows, int rowsPerBlock,
                                float* __restrict__ sums) {
  int f  = threadIdx.x % F;
  int rl = threadIdx.x / F;
  const int R = 256 / F;
  int r0 = blockIdx.x * rowsPerBlock;
  int r1 = min(r0 + rowsPerBlock, nrows);
  float s = 0.f, q = 0.f;
  for (int r = r0 + rl; r < r1; r += R) {
    float v = h[(size_t)r * F + f];
    s += v; q += v * v;
  }
  atomicAdd(&sums[f], s);
  atomicAdd(&sums[F + f], q);
}

// Fused BN finalize + bias fold: cvec = base + shvec@W; svec out.
template<int K>
__global__ void bn_fin_fold_kernel(const float* __restrict__ sums, const float* __restrict__ g,
                                   const float* __restrict__ b, int nrows,
                                   const float* __restrict__ W, const float* __restrict__ base,
                                   float* __restrict__ svec, float* __restrict__ cvec) {
  __shared__ float sh[K];
  int t = threadIdx.x;
  float mean = sums[t] / (float)nrows;
  float var  = sums[K + t] / (float)nrows - mean * mean;
  var = fmaxf(var, 0.f);
  float sc = g[t] * rsqrtf(var + EPSV);
  svec[t] = sc;
  sh[t] = b[t] - mean * sc;
  __syncthreads();
  if (t < HDIM) {
    float acc = base ? base[t] : 0.f;
#pragma unroll 8
    for (int k = 0; k < K; ++k) acc += sh[k] * W[(size_t)k * HDIM + t];
    cvec[t] = acc;
  }
}

// ---------------- GEMM: 128x128 tile, BK=8, 8x8/thread ----------------
// OBF: write bf16 (packed) instead of fp32.
template<int K, bool RELU, bool OBF>
__launch_bounds__(256)
__global__ void gemm_affine_kernel(const float* __restrict__ A, const float* __restrict__ W,
                                   const float* __restrict__ svec,
                                   const float* __restrict__ bias, void* __restrict__ outv,
                                   int nrows) {
  __shared__ float As[8][128];
  __shared__ float Bs[8][128];
  const int t  = threadIdx.x;
  const int tx = t & 15;
  const int ty = t >> 4;
  const int rowBase = blockIdx.x * 128;

  float acc[8][8];
#pragma unroll
  for (int i = 0; i < 8; ++i)
#pragma unroll
    for (int j = 0; j < 8; ++j) acc[i][j] = 0.f;

  const int arow = t >> 1;
  const int akk  = (t & 1) * 4;
  const int bkk  = t >> 5;
  const int bc   = (t & 31) * 4;

  for (int k0 = 0; k0 < K; k0 += 8) {
    {
      int gr = rowBase + arow;
      float4 v = make_float4(0.f, 0.f, 0.f, 0.f);
      if (gr < nrows) {
        v = *(const float4*)&A[(size_t)gr * K + (k0 + akk)];
        float4 sv = *(const float4*)&svec[k0 + akk];
        v.x *= sv.x; v.y *= sv.y; v.z *= sv.z; v.w *= sv.w;
      }
      As[akk + 0][arow] = v.x;
      As[akk + 1][arow] = v.y;
      As[akk + 2][arow] = v.z;
      As[akk + 3][arow] = v.w;
    }
    *(float4*)&Bs[bkk][bc] = *(const float4*)&W[(size_t)(k0 + bkk) * HDIM + bc];
    __syncthreads();
#pragma unroll
    for (int kk = 0; kk < 8; ++kk) {
      float4 a0 = *(const float4*)&As[kk][ty * 8];
      float4 a1 = *(const float4*)&As[kk][ty * 8 + 4];
      float4 b0 = *(const float4*)&Bs[kk][tx * 8];
      float4 b1 = *(const float4*)&Bs[kk][tx * 8 + 4];
      float ar[8] = {a0.x, a0.y, a0.z, a0.w, a1.x, a1.y, a1.z, a1.w};
      float br[8] = {b0.x, b0.y, b0.z, b0.w, b1.x, b1.y, b1.z, b1.w};
#pragma unroll
      for (int i = 0; i < 8; ++i)
#pragma unroll
        for (int j = 0; j < 8; ++j) acc[i][j] += ar[i] * br[j];
    }
    __syncthreads();
  }

  float bvv[8];
#pragma unroll
  for (int j = 0; j < 8; ++j) bvv[j] = bias[tx * 8 + j];
#pragma unroll
  for (int i = 0; i < 8; ++i) {
    int gr = rowBase + ty * 8 + i;
    if (gr < nrows) {
      float o[8];
#pragma unroll
      for (int j = 0; j < 8; ++j) {
        o[j] = acc[i][j] + bvv[j];
        if (RELU) o[j] = fmaxf(o[j], 0.f);
      }
      if (OBF) {
        ushort_t* outb = (ushort_t*)outv;
        uint4 w;
        w.x = (uint_t)f2bf(o[0]) | ((uint_t)f2bf(o[1]) << 16);
        w.y = (uint_t)f2bf(o[2]) | ((uint_t)f2bf(o[3]) << 16);
        w.z = (uint_t)f2bf(o[4]) | ((uint_t)f2bf(o[5]) << 16);
        w.w = (uint_t)f2bf(o[6]) | ((uint_t)f2bf(o[7]) << 16);
        *(uint4*)&outb[(size_t)gr * HDIM + tx * 8] = w;
      } else {
        float* outf = (float*)outv;
        float4 o0 = make_float4(o[0], o[1], o[2], o[3]);
        float4 o1 = make_float4(o[4], o[5], o[6], o[7]);
        *(float4*)&outf[(size_t)gr * HDIM + tx * 8]     = o0;
        *(float4*)&outf[(size_t)gr * HDIM + tx * 8 + 4] = o1;
      }
    }
  }
}

// ---------------- degree / norm ----------------
__global__ void init_deg_kernel(float* __restrict__ deg, int n) {
  int i = blockIdx.x * blockDim.x + threadIdx.x;
  if (i < n) deg[i] = 1.0f;
}
__global__ void deg_atomic_kernel(const int* __restrict__ dst, float* __restrict__ deg, int E) {
  int e = blockIdx.x * blockDim.x + threadIdx.x;
  if (e < E) atomicAdd(&deg[dst[e]], 1.0f);
}
__global__ void dinv_kernel(float* __restrict__ deg, int n) {
  int i = blockIdx.x * blockDim.x + threadIdx.x;
  if (i < n) deg[i] = rsqrtf(fmaxf(deg[i], 1.0f));
}

// ---------------- CSR build ----------------
__global__ __launch_bounds__(1024)
void scan_offsets_kernel(const float* __restrict__ deg, int n,
                         int* __restrict__ offs, int* __restrict__ cursor) {
  __shared__ int woff_s[16];
  __shared__ int btot;
  __shared__ int carry;
  const int t = threadIdx.x;
  const int lane = t & 63;
  const int wv = t >> 6;
  if (t == 0) carry = 0;
  __syncthreads();
  for (int base = 0; base < n; base += 1024) {
    int i = base + t;
    int v = (i < n) ? ((int)(deg[i] + 0.5f) - 1) : 0;
    int incl = v;
#pragma unroll
    for (int o = 1; o < 64; o <<= 1) {
      int y = __shfl_up(incl, o);
      if (lane >= o) incl += y;
    }
    if (lane == 63) woff_s[wv] = incl;
    __syncthreads();
    if (t < 16) {
      int x = woff_s[t];
      int xin = x;
#pragma unroll
      for (int o = 1; o < 16; o <<= 1) {
        int y = __shfl_up(xin, o);
        if (t >= o) xin += y;
      }
      woff_s[t] = xin - x;
      if (t == 15) btot = xin;
    }
    __syncthreads();
    int excl = carry + woff_s[wv] + (incl - v);
    if (i < n) { offs[i] = excl; cursor[i] = excl; }
    __syncthreads();
    if (t == 0) carry += btot;
    __syncthreads();
  }
  if (t == 0) offs[n] = carry;
}

__global__ void csr_fill_kernel(const int* __restrict__ src, const int* __restrict__ dst,
                                const float* __restrict__ dinv, int* __restrict__ cursor,
                                int* __restrict__ eperm, float* __restrict__ wperm, int E) {
  int e = blockIdx.x * blockDim.x + threadIdx.x;
  if (e >= E) return;
  int s = src[e], d = dst[e];
  int slot = atomicAdd(&cursor[d], 1);
  eperm[slot] = s;
  wperm[slot] = dinv[s] * dinv[d];
}

// ---------------- fused propagation (bf16 t-table): self-loop+gather+bias(+relu)
// One wave per node; lane l holds feats [2l,2l+1] (one uint per row per lane).
// OBF: write h as bf16 (final layer, feeds edge_score); else fp32.
template<bool OBF>
__global__ __launch_bounds__(256)
void gcn_gather_kernel(const ushort_t* __restrict__ t16, const int* __restrict__ offs,
                       const int* __restrict__ eperm, const float* __restrict__ wperm,
                       const float* __restrict__ dinv, const float* __restrict__ bias,
                       void* __restrict__ outv, int n, int relu) {
  int gw = (int)((blockIdx.x * blockDim.x + threadIdx.x) >> 6);
  int lane = threadIdx.x & 63;
  if (gw >= n) return;
  float w0 = dinv[gw]; w0 *= w0;
  uint_t tv = *(const uint_t*)&t16[(size_t)gw * HDIM + lane * 2];
  float ax = w0 * bf2f(tv & 0xFFFFu), ay = w0 * bf2f(tv >> 16);
  int e = offs[gw], e1 = offs[gw + 1];
  for (; e + 3 < e1; e += 4) {
    int s0 = eperm[e], s1 = eperm[e + 1], s2 = eperm[e + 2], s3 = eperm[e + 3];
    float wa = wperm[e], wb = wperm[e + 1], wc = wperm[e + 2], wd = wperm[e + 3];
    uint_t v0 = *(const uint_t*)&t16[(size_t)s0 * HDIM + lane * 2];
    uint_t v1 = *(const uint_t*)&t16[(size_t)s1 * HDIM + lane * 2];
    uint_t v2 = *(const uint_t*)&t16[(size_t)s2 * HDIM + lane * 2];
    uint_t v3 = *(const uint_t*)&t16[(size_t)s3 * HDIM + lane * 2];
    ax += wa * bf2f(v0 & 0xFFFFu) + wb * bf2f(v1 & 0xFFFFu)
        + wc * bf2f(v2 & 0xFFFFu) + wd * bf2f(v3 & 0xFFFFu);
    ay += wa * bf2f(v0 >> 16) + wb * bf2f(v1 >> 16)
        + wc * bf2f(v2 >> 16) + wd * bf2f(v3 >> 16);
  }
  for (; e < e1; ++e) {
    int s0 = eperm[e]; float wa = wperm[e];
    uint_t v0 = *(const uint_t*)&t16[(size_t)s0 * HDIM + lane * 2];
    ax += wa * bf2f(v0 & 0xFFFFu); ay += wa * bf2f(v0 >> 16);
  }
  ax += bias[lane * 2]; ay += bias[lane * 2 + 1];
  if (relu) { ax = fmaxf(ax, 0.f); ay = fmaxf(ay, 0.f); }
  if (OBF) {
    ushort_t* outb = (ushort_t*)outv;
    uint_t w = (uint_t)f2bf(ax) | ((uint_t)f2bf(ay) << 16);
    *(uint_t*)&outb[(size_t)gw * HDIM + lane * 2] = w;
  } else {
    float* outf = (float*)outv;
    float2 o; o.x = ax; o.y = ay;
    *(float2*)&outf[(size_t)gw * HDIM + lane * 2] = o;
  }
}

// ---------------- link scoring on bf16 h ----------------
__global__ void edge_score_kernel(const int* __restrict__ src, const int* __restrict__ dst,
                                  const ushort_t* __restrict__ h16, float* __restrict__ out, int E) {
  int g = blockIdx.x * blockDim.x + threadIdx.x;
  int e = g >> 6;
  int l = g & 63;
  if (e >= E) return;
  int s = src[e], d = dst[e];
  uint_t a = *(const uint_t*)&h16[(size_t)s * HDIM + l * 2];
  uint_t b = *(const uint_t*)&h16[(size_t)d * HDIM + l * 2];
  float sum = bf2f(a & 0xFFFFu) * bf2f(b & 0xFFFFu) + bf2f(a >> 16) * bf2f(b >> 16);
#pragma unroll
  for (int off = 32; off >= 1; off >>= 1) sum += __shfl_xor(sum, off);
  if (l == 0) out[e] = 1.0f / (1.0f + expf(-sum));
}

// ---------------- launch ----------------
extern "C" void kernel_launch(void* const* d_in, const int* in_sizes, int n_in,
                              void* d_out, int out_size, void* d_ws, size_t ws_size,
                              hipStream_t stream) {
  const float* x     = (const float*)d_in[0];
  const void*  ei    = d_in[1];
  const float* bn_g  = (const float*)d_in[2];
  const float* bn_b  = (const float*)d_in[3];
  const float* Wf    = (const float*)d_in[4];
  const float* bf    = (const float*)d_in[5];
  const float* bns_g = (const float*)d_in[6];
  const float* bns_b = (const float*)d_in[7];
  const float* Ws    = (const float*)d_in[8];
  const float* bs    = (const float*)d_in[9];
  float* score_out   = (float*)d_out;

  const int N = in_sizes[0] / F_INC;
  const int E = in_sizes[1] / 2;

  const size_t nh = (size_t)N * HDIM;
  float* ws     = (float*)d_ws;
  float* bufA   = ws;                  // fp32 h
  float* bufB   = bufA + nh;           // t16 lives here (bf16, half used)
  float* bufC   = bufB + nh;           // fp32 h / final bf16 h
  float* dinv   = bufC + nh;
  float* sums   = dinv + N;
  float* svec   = sums + 2 * F_INC;
  float* shvec  = svec + F_INC;        // layout kept
  float* cvec   = shvec + F_INC;
  int*   src    = (int*)(cvec + HDIM);
  int*   dst    = src + E;
  int*   flag   = dst + E;
  int*   offs   = flag + 1;
  int*   cursor = offs + (N + 1);
  int*   eperm  = cursor + N;
  float* wperm  = (float*)(eperm + E);

  ushort_t* t16 = (ushort_t*)bufB;

  const int nB = (N + 255) / 256;
  const int eB = (E + 255) / 256;
  const int gB = (N + 127) / 128;
  const int rpb = (N + 255) / 256;
  const int gatherB = (N + 3) / 4;

  hipMemsetAsync(flag, 0, sizeof(int), stream);
  detect_i64_kernel<<<eB, 256, 0, stream>>>((const long long*)ei, E, N, flag);
  convert_idx_kernel<<<eB, 256, 0, stream>>>(ei, E, flag, src, dst);

  init_deg_kernel<<<nB, 256, 0, stream>>>(dinv, N);
  deg_atomic_kernel<<<eB, 256, 0, stream>>>(dst, dinv, E);
  scan_offsets_kernel<<<1, 1024, 0, stream>>>(dinv, N, offs, cursor);
  dinv_kernel<<<nB, 256, 0, stream>>>(dinv, N);
  csr_fill_kernel<<<eB, 256, 0, stream>>>(src, dst, dinv, cursor, eperm, wperm, E);

  // feature BN (folded) + feature GEMM + relu -> fp32 h in bufA
  hipMemsetAsync(sums, 0, 2 * F_INC * sizeof(float), stream);
  bn_stats_kernel<F_INC><<<256, 256, 0, stream>>>(x, N, rpb, sums);
  bn_fin_fold_kernel<F_INC><<<1, F_INC, 0, stream>>>(sums, bn_g, bn_b, N, Wf, bf, svec, cvec);
  gemm_affine_kernel<F_INC, true, false><<<gB, 256, 0, stream>>>(x, Wf, svec, cvec, bufA, N);

  float* h    = bufA;
  float* obuf = bufC;

  for (int i = 0; i < NLAYER; ++i) {
    const float* Wi = Ws + (size_t)i * HDIM * HDIM;
    const bool last = (i == NLAYER - 1);
    hipMemsetAsync(sums, 0, 2 * HDIM * sizeof(float), stream);
    bn_stats_kernel<HDIM><<<256, 256, 0, stream>>>(h, N, rpb, sums);
    bn_fin_fold_kernel<HDIM><<<1, HDIM, 0, stream>>>(sums, bns_g + i * HDIM, bns_b + i * HDIM,
                                                     N, Wi, nullptr, svec, cvec);
    // GEMM -> bf16 t-table
    gemm_affine_kernel<HDIM, false, true><<<gB, 256, 0, stream>>>(h, Wi, svec, cvec, t16, N);
    // gather: intermediate layers -> fp32 h; last layer -> bf16 h
    if (!last) {
      gcn_gather_kernel<false><<<gatherB, 256, 0, stream>>>(t16, offs, eperm, wperm, dinv,
                                                            bs + i * HDIM, obuf, N, 1);
      float* tmp = h; h = obuf; obuf = tmp;
    } else {
      gcn_gather_kernel<true><<<gatherB, 256, 0, stream>>>(t16, offs, eperm, wperm, dinv,
                                                           bs + i * HDIM, obuf, N, 0);
    }
  }

  // h (bf16) is in obuf after the last layer
  {
    long long tt = (long long)E * 64;
    int eb2 = (int)((tt + 255) / 256);
    edge_score_kernel<<<eb2, 256, 0, stream>>>(src, dst, (const ushort_t*)obuf, score_out, E);
  }
}